// Round 7
// baseline (289.278 us; speedup 1.0000x reference)
//
#include <hip/hip_runtime.h>
#include <hip/hip_bf16.h>

typedef unsigned short u16;
typedef unsigned int   u32;
typedef unsigned long long u64;
typedef __bf16 bf16x8 __attribute__((ext_vector_type(8)));
typedef float  f32x4  __attribute__((ext_vector_type(4)));

#define S_LEN  2048
#define BATCH  2
#define DMODEL 1024
#define NHEADS 16
#define DKH    64
#define MWORDS (S_LEN/64)
#define ATT_SCALE 0.125f
#define C2EXP 0.18033688011112f   // ATT_SCALE * log2(e)

__device__ __forceinline__ u16 f2bf(float f){
  u32 x = __builtin_bit_cast(u32, f);
  x += 0x7fffu + ((x >> 16) & 1u);   // RNE
  return (u16)(x >> 16);
}
__device__ __forceinline__ bf16x8 ld8(const u16* p){ return *(const bf16x8*)p; }

// async global->LDS, 16B per lane. HW: dest = wave-uniform base + lane*16.
__device__ __forceinline__ void gload16(const u16* g, u16* l){
  __builtin_amdgcn_global_load_lds(
      (const __attribute__((address_space(1))) u32*)(u64)g,
      (__attribute__((address_space(3))) u32*)(u64)l,
      16, 0, 0);
}

// ---- fp32->bf16 bulk conversion + mask bit-packing (unchanged, passing) ----
__global__ __launch_bounds__(256) void cvt_kernel(
    const float* __restrict__ a0, const float* __restrict__ a1, const float* __restrict__ a2,
    const float* __restrict__ wi, const float* __restrict__ wo, const int* __restrict__ msk,
    u16* __restrict__ d0, u16* __restrict__ d1, u16* __restrict__ d2,
    u16* __restrict__ dwi, u16* __restrict__ dwo, u64* __restrict__ mbits)
{
  int tid = blockIdx.x*256 + threadIdx.x;
  int stride = gridDim.x*256;
  const int NX = S_LEN*BATCH*DMODEL/4;
  for (int i = tid; i < NX; i += stride){
    f32x4 x0 = ((const f32x4*)a0)[i];
    f32x4 x1 = ((const f32x4*)a1)[i];
    f32x4 x2 = ((const f32x4*)a2)[i];
    ((ushort4*)d0)[i] = make_ushort4(f2bf(x0[0]), f2bf(x0[1]), f2bf(x0[2]), f2bf(x0[3]));
    ((ushort4*)d1)[i] = make_ushort4(f2bf(x1[0]), f2bf(x1[1]), f2bf(x1[2]), f2bf(x1[3]));
    ((ushort4*)d2)[i] = make_ushort4(f2bf(x2[0]), f2bf(x2[1]), f2bf(x2[2]), f2bf(x2[3]));
  }
  const int NWI = 3*DMODEL*DMODEL/4;
  for (int i = tid; i < NWI; i += stride){
    f32x4 x = ((const f32x4*)wi)[i];
    ((ushort4*)dwi)[i] = make_ushort4(f2bf(x[0]), f2bf(x[1]), f2bf(x[2]), f2bf(x[3]));
  }
  const int NWO = DMODEL*DMODEL/4;
  for (int i = tid; i < NWO; i += stride){
    f32x4 x = ((const f32x4*)wo)[i];
    ((ushort4*)dwo)[i] = make_ushort4(f2bf(x[0]), f2bf(x[1]), f2bf(x[2]), f2bf(x[3]));
  }
  int gw   = tid >> 6;
  int lane = threadIdx.x & 63;
  int nwaves = stride >> 6;
  const int NW = BATCH*S_LEN*MWORDS;
  for (int w = gw; w < NW; w += nwaves){
    int v = msk[(size_t)w*64 + lane];
    u64 bits = __ballot(v != 0);
    if (lane == 0) mbits[w] = bits;
  }
}

// ---- m97-style 128x128 block GEMM mainloop (unchanged, passing) ----
__device__ __forceinline__ void gemm128_loop(
    const u16* __restrict__ A, const u16* __restrict__ W,
    u16* abuf, u16* bbuf, int tid, f32x4 acc[4][4])
{
  int lane = tid & 63, quad = lane >> 4, r = lane & 15;
  int wv = tid >> 6, wm = (wv & 1)*64, wn = (wv >> 1)*64;
  int c0 = tid, c1 = tid + 256;
  int r0 = c0 >> 2, g0 = ((c0 & 3) ^ (r0 & 3))*8;
  int r1 = c1 >> 2, g1 = ((c1 & 3) ^ (r1 & 3))*8;
  const u16* ga0 = A + (size_t)r0*DMODEL + g0;
  const u16* ga1 = A + (size_t)r1*DMODEL + g1;
  const u16* gb0 = W + (size_t)r0*DMODEL + g0;
  const u16* gb1 = W + (size_t)r1*DMODEL + g1;
  u16* la0 = abuf + c0*8;  u16* la1 = abuf + c1*8;
  u16* lb0 = bbuf + c0*8;  u16* lb1 = bbuf + c1*8;
  int sw = (quad ^ (r & 3))*8;

  for (int k0 = 0; k0 < DMODEL; k0 += 32){
    __syncthreads();
    gload16(ga0 + k0, la0);
    gload16(ga1 + k0, la1);
    gload16(gb0 + k0, lb0);
    gload16(gb1 + k0, lb1);
    __syncthreads();
    bf16x8 af[4], bfr[4];
    #pragma unroll
    for (int i = 0; i < 4; ++i) af[i]  = ld8(&abuf[(wm + i*16 + r)*32 + sw]);
    #pragma unroll
    for (int i = 0; i < 4; ++i) bfr[i] = ld8(&bbuf[(wn + i*16 + r)*32 + sw]);
    #pragma unroll
    for (int mi = 0; mi < 4; ++mi)
      #pragma unroll
      for (int ni = 0; ni < 4; ++ni)
        acc[mi][ni] = __builtin_amdgcn_mfma_f32_16x16x32_bf16(af[mi], bfr[ni], acc[mi][ni], 0,0,0);
  }
}

// QKV projection (unchanged, passing)
__global__ __launch_bounds__(256) void qkv_proj_kernel(
    const u16* __restrict__ xq, const u16* __restrict__ xk, const u16* __restrict__ xv,
    const u16* __restrict__ w, const float* __restrict__ bias,
    u16* __restrict__ q_ws, u16* __restrict__ k_ws, u16* __restrict__ vt_ws)
{
  __shared__ __align__(16) u16 abuf[128*32];
  __shared__ __align__(16) u16 bbuf[128*32];
  int tid = threadIdx.x;
  int lane = tid & 63, quad = lane >> 4, r = lane & 15;
  int wv = tid >> 6, wm = (wv & 1)*64, wn = (wv >> 1)*64;
  int m0 = blockIdx.x*128, n0 = blockIdx.y*128;
  int t = n0 >> 10;
  const u16* X = (t == 0) ? xq : (t == 1) ? xk : xv;

  f32x4 acc[4][4] = {};
  gemm128_loop(X + (size_t)m0*DMODEL, w + (size_t)n0*DMODEL, abuf, bbuf, tid, acc);

  int mbase = m0 + wm, nbase = n0 + wn;
  #pragma unroll
  for (int ni = 0; ni < 4; ++ni){
    int n  = nbase + ni*16 + r;
    float bv = bias[n];
    int nn = n & (DMODEL-1);
    int h = nn >> 6, dk = nn & 63;
    #pragma unroll
    for (int mi = 0; mi < 4; ++mi){
      #pragma unroll
      for (int reg = 0; reg < 4; ++reg){
        int m = mbase + mi*16 + quad*4 + reg;
        int s = m >> 1, b = m & 1;
        u16 hv = f2bf(acc[mi][ni][reg] + bv);
        size_t bh = (size_t)(b*NHEADS + h);
        if (t == 0)      q_ws [(bh*S_LEN + s)*DKH + dk] = hv;
        else if (t == 1) k_ws [(bh*S_LEN + s)*DKH + dk] = hv;
        else             vt_ws[(bh*DKH + dk)*S_LEN + s] = hv;
      }
    }
  }
}

// Flash attention: K/V tiles staged in MFMA-fragment chunk order via
// global_load_lds (lane-contiguous LDS, conflict-free b128 reads).
// chunk n = (t*2+half)*64 + quad*16 + r holds:
//   K: K[j0+16t+r][half*32+quad*8 ..+7]   (A-frag for S^T tile t, half)
//   V: Vt[16t+r][j0+half*32+quad*8 ..+7]  (B-frag for PV tile t, half)
__global__ __launch_bounds__(256) void attn_kernel(
    const u16* __restrict__ q_ws, const u16* __restrict__ k_ws, const u16* __restrict__ vt_ws,
    const u64* __restrict__ mbits, u16* __restrict__ x_ws)
{
  __shared__ __align__(16) u16 kperm[64*64];
  __shared__ __align__(16) u16 vperm[64*64];
  __shared__ __align__(16) u16 pbuf[4][16*72];
  int tid  = threadIdx.x;
  int wv   = tid >> 6;
  int lane = tid & 63;
  int quad = lane >> 4, r = lane & 15;
  int bh = blockIdx.y;
  int b  = bh >> 4, h = bh & 15;
  int i0 = (blockIdx.x*4 + wv) * 16;

  const u16* Q  = q_ws  + (size_t)bh*S_LEN*DKH;
  const u16* K  = k_ws  + (size_t)bh*S_LEN*DKH;
  const u16* Vt = vt_ws + (size_t)bh*DKH*S_LEN;
  const u64* MB = mbits + ((size_t)b*S_LEN + (i0 + r))*MWORDS;

  // wave wv stages chunks [wv*128, wv*128+128): rows j0+16wv+r (K) / 16wv+r (Vt),
  // call0 = cols 0..31 (half 0), call1 = cols 32..63 (half 1); col quad*8 per lane.
  const u16* gk0 = K  + (size_t)(16*wv + r)*DKH + quad*8;         // += 64*DKH/iter
  const u16* gk1 = gk0 + 32;
  const u16* gv0 = Vt + (size_t)(16*wv + r)*S_LEN + quad*8;       // += 64/iter
  const u16* gv1 = gv0 + 32;
  u16* lk = kperm + (size_t)wv*128*8;
  u16* lv = vperm + (size_t)wv*128*8;

  const u16* qrow = Q + (size_t)(i0 + r)*DKH + quad*8;
  bf16x8 qf0 = ld8(qrow), qf1 = ld8(qrow + 32);

  float l_part = 0.f;
  f32x4 o[4] = {};
  f32x4 z = {0.f, 0.f, 0.f, 0.f};
  u16* pl = pbuf[wv];

  for (int j0 = 0; j0 < S_LEN; j0 += 64){
    u64 mb = MB[j0 >> 6];
    __syncthreads();                 // prior iter's reads of kperm/vperm done
    gload16(gk0, lk);  gload16(gk1, lk + 512);
    gload16(gv0, lv);  gload16(gv1, lv + 512);
    gk0 += 64*DKH; gk1 += 64*DKH; gv0 += 64; gv1 += 64;
    __syncthreads();                 // vmcnt drained: DMA visible

    float p[16];
    #pragma unroll
    for (int c = 0; c < 4; ++c){
      bf16x8 ka = ld8(&kperm[(2*c + 0)*512 + lane*8]);   // lane-contiguous
      bf16x8 kb = ld8(&kperm[(2*c + 1)*512 + lane*8]);
      f32x4 s = __builtin_amdgcn_mfma_f32_16x16x32_bf16(ka, qf0, z, 0,0,0);
      s       = __builtin_amdgcn_mfma_f32_16x16x32_bf16(kb, qf1, s, 0,0,0);
      u32 mc = (u32)(mb >> (16*c + 4*quad));
      p[c*4+0] = (mc & 1u) ? 0.f : __builtin_amdgcn_exp2f(s[0]*C2EXP);
      p[c*4+1] = (mc & 2u) ? 0.f : __builtin_amdgcn_exp2f(s[1]*C2EXP);
      p[c*4+2] = (mc & 4u) ? 0.f : __builtin_amdgcn_exp2f(s[2]*C2EXP);
      p[c*4+3] = (mc & 8u) ? 0.f : __builtin_amdgcn_exp2f(s[3]*C2EXP);
      l_part += p[c*4+0] + p[c*4+1] + p[c*4+2] + p[c*4+3];
    }
    // pack P pairs to bf16 via v_perm (round-half-up), store P^T -> P roundtrip
    #pragma unroll
    for (int c = 0; c < 4; ++c){
      u32 e0 = __builtin_bit_cast(u32, p[c*4+0]) + 0x8000u;
      u32 o0 = __builtin_bit_cast(u32, p[c*4+1]) + 0x8000u;
      u32 e1 = __builtin_bit_cast(u32, p[c*4+2]) + 0x8000u;
      u32 o1 = __builtin_bit_cast(u32, p[c*4+3]) + 0x8000u;
      uint2 pk;
      pk.x = __builtin_amdgcn_perm(o0, e0, 0x07060302u);   // [bf(p0), bf(p1)]
      pk.y = __builtin_amdgcn_perm(o1, e1, 0x07060302u);   // [bf(p2), bf(p3)]
      *(uint2*)&pl[r*72 + 16*c + quad*4] = pk;
    }
    asm volatile("s_waitcnt lgkmcnt(0)" ::: "memory");
    bf16x8 pf0 = ld8(&pl[r*72 + quad*8]);
    bf16x8 pf1 = ld8(&pl[r*72 + 32 + quad*8]);
    #pragma unroll
    for (int tt = 0; tt < 4; ++tt){
      bf16x8 va = ld8(&vperm[(2*tt + 0)*512 + lane*8]);    // lane-contiguous
      bf16x8 vb = ld8(&vperm[(2*tt + 1)*512 + lane*8]);
      o[tt] = __builtin_amdgcn_mfma_f32_16x16x32_bf16(pf0, va, o[tt], 0,0,0);
      o[tt] = __builtin_amdgcn_mfma_f32_16x16x32_bf16(pf1, vb, o[tt], 0,0,0);
    }
  }

  l_part += __shfl_xor(l_part, 16, 64);
  l_part += __shfl_xor(l_part, 32, 64);
  float l0 = 1.f/__shfl(l_part, quad*4+0, 64);
  float l1 = 1.f/__shfl(l_part, quad*4+1, 64);
  float l2 = 1.f/__shfl(l_part, quad*4+2, 64);
  float l3 = 1.f/__shfl(l_part, quad*4+3, 64);
  #pragma unroll
  for (int tt = 0; tt < 4; ++tt){
    int col = h*DKH + tt*16 + r;
    x_ws[((size_t)(i0 + quad*4 + 0)*BATCH + b)*DMODEL + col] = f2bf(o[tt][0]*l0);
    x_ws[((size_t)(i0 + quad*4 + 1)*BATCH + b)*DMODEL + col] = f2bf(o[tt][1]*l1);
    x_ws[((size_t)(i0 + quad*4 + 2)*BATCH + b)*DMODEL + col] = f2bf(o[tt][2]*l2);
    x_ws[((size_t)(i0 + quad*4 + 3)*BATCH + b)*DMODEL + col] = f2bf(o[tt][3]*l3);
  }
}

// Out projection (unchanged, passing)
__global__ __launch_bounds__(256) void out_proj_kernel(
    const u16* __restrict__ x, const u16* __restrict__ w, const float* __restrict__ bias,
    float* __restrict__ out)
{
  __shared__ __align__(16) u16 abuf[128*32];
  __shared__ __align__(16) u16 bbuf[128*32];
  int tid = threadIdx.x;
  int lane = tid & 63, quad = lane >> 4, r = lane & 15;
  int wv = tid >> 6, wm = (wv & 1)*64, wn = (wv >> 1)*64;
  int m0 = blockIdx.x*128, n0 = blockIdx.y*128;

  f32x4 acc[4][4] = {};
  gemm128_loop(x + (size_t)m0*DMODEL, w + (size_t)n0*DMODEL, abuf, bbuf, tid, acc);

  int mbase = m0 + wm, nbase = n0 + wn;
  #pragma unroll
  for (int ni = 0; ni < 4; ++ni){
    int n = nbase + ni*16 + r;
    float bv = bias[n];
    #pragma unroll
    for (int mi = 0; mi < 4; ++mi){
      #pragma unroll
      for (int reg = 0; reg < 4; ++reg){
        int m = mbase + mi*16 + quad*4 + reg;
        out[(size_t)m*DMODEL + n] = acc[mi][ni][reg] + bv;
      }
    }
  }
}

extern "C" void kernel_launch(void* const* d_in, const int* in_sizes, int n_in,
                              void* d_out, int out_size, void* d_ws, size_t ws_size,
                              hipStream_t stream) {
  (void)in_sizes; (void)n_in; (void)out_size; (void)ws_size;
  const float* query = (const float*)d_in[0];
  const float* key   = (const float*)d_in[1];
  const float* value = (const float*)d_in[2];
  const int*   mask  = (const int*)d_in[3];
  const float* w_in  = (const float*)d_in[4];
  const float* b_in  = (const float*)d_in[5];
  const float* w_out = (const float*)d_in[6];
  const float* b_out = (const float*)d_in[7];
  float* out = (float*)d_out;

  const size_t TSZ = (size_t)BATCH*NHEADS*S_LEN*DKH;
  const size_t XSZ = (size_t)S_LEN*BATCH*DMODEL;
  u16* q_ws  = (u16*)d_ws;
  u16* k_ws  = q_ws  + TSZ;
  u16* vt_ws = k_ws  + TSZ;
  u16* x_ws  = vt_ws + TSZ;
  u16* xq_bf = x_ws  + XSZ;
  u16* xk_bf = xq_bf + XSZ;
  u16* xv_bf = xk_bf + XSZ;
  u16* wi_bf = xv_bf + XSZ;
  u16* wo_bf = wi_bf + (size_t)3*DMODEL*DMODEL;
  u64* mb_ws = (u64*)(wo_bf + (size_t)DMODEL*DMODEL);

  cvt_kernel<<<1024, 256, 0, stream>>>(query, key, value, w_in, w_out, mask,
                                       xq_bf, xk_bf, xv_bf, wi_bf, wo_bf, mb_ws);
  qkv_proj_kernel<<<dim3(32, 24), 256, 0, stream>>>(xq_bf, xk_bf, xv_bf, wi_bf, b_in,
                                                    q_ws, k_ws, vt_ws);
  attn_kernel<<<dim3(32, 32), 256, 0, stream>>>(q_ws, k_ws, vt_ws, mb_ws, x_ws);
  out_proj_kernel<<<dim3(32, 8), 256, 0, stream>>>(x_ws, wo_bf, b_out, out);
}